// Round 1
// 115.049 us; speedup vs baseline: 1.0198x; 1.0198x over previous
//
#include <hip/hip_runtime.h>

#define BATCH_N 65536
#define SEQ_N   128

// Native clang vector type — accepted by __builtin_nontemporal_load/store.
typedef float v2f __attribute__((ext_vector_type(2)));

// One thread per batch element; 128-step sequential recurrence in registers.
// 1 wave/SIMD (65536 lanes / 1024 SIMDs) → no TLP. Latency hiding comes from
// a depth-2 chunk pipeline: raw buffers are reloaded the moment preC consumes
// them, so there are ALWAYS >=16 loads (one 16-row chunk) in flight; the
// load->use distance is ~2 stepC + 1 preC (~2500 cy >> ~900 cy HBM latency).
// Everything derivable from ratings alone (d-chain, success multiplier
// (11-d)*hb, failure multiplier w11*d^-w12) is precomputed off the s-chain's
// critical path; the branch flag rides in sign(M).
// Hot-phase step: 4 transcendentals (rcp, 1x log2, 2x exp2) + ~16 VALU —
// the two mutually-exclusive logs (log s vs log(s+1)) are merged via a
// select on the precomputed branch flag, and the final clamps are split
// per-branch (success can't underflow S_MIN; failure can't exceed s<=S_MAX).
__global__ __launch_bounds__(256, 1) void fsrs_kernel(
    const v2f* __restrict__ in,   // (SEQ, BATCH) of (t, rating)
    const float* __restrict__ w,  // 17 weights
    v2f*       __restrict__ out)  // (SEQ, BATCH) of (s, d) then (BATCH) final
{
    const int b = blockIdx.x * 256 + threadIdx.x;

    const float w0 = w[0], w1 = w[1], w2 = w[2], w3 = w[3];
    const float w4 = w[4], w5 = w[5], w6 = w[6], w7 = w[7];
    const float w9 = w[9], w11 = w[11], w12 = w[12], w13 = w[13];
    const float w15 = w[15], w16 = w[16];
    constexpr float LOG2E = 1.44269504088896340736f;
    const float w8l  = w[8]  * LOG2E;   // exp(w8)*s^-w9 = exp2(w8l - w9*log2 s)
    const float w10l = w[10] * LOG2E;
    const float w14l = w[14] * LOG2E;
    const float omw7   = 1.0f - w7;
    const float omw7w6 = omw7 * w6;
    const float dc0    = w7 * w4 + 3.0f * omw7w6;

    const v2f* ip = in  + b;
    v2f*       op = out + b;

    float s = 0.01f;       // stability state
    float dpre = 1.0f;     // d running ahead (precompute timing)

    v2f rawA[16], rawB[16];
    float tA[16], dA[16], mA[16];   // t, new-d (output), merged multiplier
    float tB[16], dB[16], mB[16];

    auto loadC = [&](v2f* raw, int base) {
#pragma unroll
        for (int i = 0; i < 16; ++i) raw[i] = ip[(base + i) * BATCH_N];
    };

    // Precompute rows [lo,16) of a chunk. Uses/updates dpre (old d on entry
    // to each row). M[i] = success ? (11-d_old)*hb : -(w11*d_old^-w12);
    // sign(M) encodes the branch ((11-d)>=1>0 and w11*d^-w12>0 always).
    auto preC = [&](const v2f* raw, float* T, float* D, float* M, int lo) {
#pragma unroll
        for (int i = 0; i < 16; ++i) {
            if (i < lo) continue;
            const float tt = raw[i].x, rating = raw[i].y;
            const float hb = (rating == 2.0f) ? w15
                           : ((rating == 4.0f) ? w16 : 1.0f);
            const float eh = (11.0f - dpre) * hb;
            const float m2 = w11 * __builtin_amdgcn_exp2f(
                                 -w12 * __builtin_amdgcn_logf(dpre));
            M[i] = (rating > 1.0f) ? eh : -m2;
            const float nd = __builtin_fmaf(omw7, dpre,
                              __builtin_fmaf(-omw7w6, rating, dc0));
            dpre = fminf(fmaxf(nd, 1.0f), 10.0f);
            T[i] = tt;
            D[i] = dpre;
        }
    };

    // Hot phase: s-recurrence + store. All rating/d-dependent terms arrive
    // precomputed; only the s-chain runs here. Single log: the branch is
    // known up front (sign of M), so log2(sel ? s : s+1) serves both
    // s^-w9 (success) and (s+1)^w13 (failure).
    auto stepC = [&](const float* T, const float* D, const float* M,
                     int base, int lo) {
#pragma unroll
        for (int i = 0; i < 16; ++i) {
            if (i < lo) continue;
            const float tt = T[i], ms = M[i];
            const bool  sel = ms > 0.0f;                    // success?
            const float q   = __builtin_fmaf(9.0f, s, tt);  // 9s + t
            const float omr = tt * __builtin_amdgcn_rcpf(q);// 1 - r
            const float e   = __builtin_amdgcn_exp2f(omr * (sel ? w10l : w14l));
            const float ls  = __builtin_amdgcn_logf(sel ? s : (s + 1.0f));
            const float aa  = sel ? __builtin_fmaf(-w9, ls, w8l) : (w13 * ls);
            const float A   = __builtin_amdgcn_exp2f(aa);
            const float Af  = sel ? A          : (A - 1.0f);
            const float Ef  = sel ? (e - 1.0f) : e;
            const float m   = sel ? (ms * s)   : (-ms);
            const float P   = Af * Ef * m;
            // success: s+P >= s >= 0.01 already; failure: min(P,s) <= s <= 36500.
            const float su  = fminf(s + P, 36500.0f);
            const float fl  = fmaxf(fminf(P, s), 0.01f);
            s = sel ? su : fl;
            v2f o; o.x = s; o.y = D[i];
            __builtin_nontemporal_store(o, &op[(base + i) * BATCH_N]);
        }
    };

    // ---- prologue: chunks ch0 (rows 0..15), ch1 (16..31) ----
    loadC(rawA, 0);
    loadC(rawB, 16);

    const float t0 = rawA[0].x, r0 = rawA[0].y;
    {   // row 0: _first_step (d0 comes from rating only)
        const float d0 = fminf(fmaxf(
            __builtin_fmaf(-w5, r0 - 3.0f, w4), 1.0f), 10.0f);
        dpre = d0;
        tA[0] = t0; dA[0] = d0; mA[0] = 1.0f;
    }
    preC(rawA, tA, dA, mA, 1);     // ch0 — rawA free after this
    loadC(rawA, 32);               // ch2 in flight

    {   // step row 0 (special): s0 from weight table
        const float wsel = (r0 < 2.5f) ? ((r0 < 1.5f) ? w0 : w1)
                                       : ((r0 < 3.5f) ? w2 : w3);
        const float ns = (r0 >= 1.0f && r0 <= 4.0f) ? wsel : 1.0f;
        s = fminf(fmaxf(ns, 0.01f), 36500.0f);
        v2f o; o.x = s; o.y = dA[0];
        __builtin_nontemporal_store(o, &op[0]);
    }
    stepC(tA, dA, mA, 0, 1);       // ch0 rows 1..15
    preC(rawB, tB, dB, mB, 0);     // ch1 — rawB free after this
    loadC(rawB, 48);               // ch3 in flight
    // steady-state invariant at loop top: tB = pre'd ch(2c+1);
    // rawA = ch(2c+2), rawB = ch(2c+3) in flight (loaded >=1 chunk ago).

    // ---- main: c=0 handles ch1/ch2 (+loads ch4,ch5); c=1 ch3/ch4 (+ch6,ch7)
#pragma unroll 1
    for (int c = 0; c < 2; ++c) {
        stepC(tB, dB, mB, 16 + 32 * c, 0);   // ch 2c+1
        preC(rawA, tA, dA, mA, 0);           // ch 2c+2 — rawA free
        loadC(rawA, 64 + 32 * c);            // ch 2c+4
        stepC(tA, dA, mA, 32 + 32 * c, 0);   // ch 2c+2
        preC(rawB, tB, dB, mB, 0);           // ch 2c+3 — rawB free
        loadC(rawB, 80 + 32 * c);            // ch 2c+5
    }

    // ---- tail: ch5, ch6, ch7 (all loads already in flight) ----
    stepC(tB, dB, mB, 80, 0);      // ch5
    preC(rawA, tA, dA, mA, 0);     // ch6
    stepC(tA, dA, mA, 96, 0);      // ch6
    preC(rawB, tB, dB, mB, 0);     // ch7
    stepC(tB, dB, mB, 112, 0);     // ch7

    // final_state, appended after the (SEQ, BATCH) outputs.
    {
        v2f o; o.x = s; o.y = dB[15];
        op[SEQ_N * BATCH_N] = o;
    }
}

extern "C" void kernel_launch(void* const* d_in, const int* in_sizes, int n_in,
                              void* d_out, int out_size, void* d_ws, size_t ws_size,
                              hipStream_t stream) {
    const v2f*   in = (const v2f*)d_in[0];   // (128, 65536, 2) f32
    const float* w  = (const float*)d_in[1]; // (17,) f32
    v2f* out = (v2f*)d_out;                  // 128*65536 + 65536 float2
    fsrs_kernel<<<BATCH_N / 256, 256, 0, stream>>>(in, w, out);
}